// Round 2
// baseline (3632.347 us; speedup 1.0000x reference)
//
#include <hip/hip_runtime.h>

// dims
#define BB 2
#define TT 2048
#define HID 2048
#define HK 16
#define HV 32
#define DK 128
#define DV 128
#define KW 4
#define KEY_DIM 2048
#define VAL_DIM 4096
#define CONV_DIM 8192
#define N1PAD 12416     // 12352 padded to 128
#define M_ROWS 4096     // B*T

typedef __attribute__((ext_vector_type(8))) short short8;
typedef __attribute__((ext_vector_type(8))) unsigned short ushort8;
typedef __attribute__((ext_vector_type(4))) float f32x4;

__device__ __forceinline__ unsigned short f2bf(float f) {
  union { float f; unsigned int u; } v; v.f = f;
  unsigned int r = v.u + 0x7FFFu + ((v.u >> 16) & 1u);
  return (unsigned short)(r >> 16);
}
__device__ __forceinline__ float bf2f(unsigned short u) {
  union { unsigned int u; float f; } v; v.u = ((unsigned int)u) << 16; return v.f;
}

__device__ __forceinline__ void gload_lds16(const unsigned short* g, unsigned short* l) {
  __builtin_amdgcn_global_load_lds((const __attribute__((address_space(1))) unsigned int*)g,
                                   (__attribute__((address_space(3))) unsigned int*)l,
                                   16, 0, 0);
}

// ---------------- conversions ----------------
__global__ void cvt_bf16(const float* __restrict__ in, unsigned short* __restrict__ out) {
  long i = ((long)blockIdx.x * 256 + threadIdx.x) * 4;
  float4 v = *(const float4*)&in[i];
  unsigned long long p = (unsigned long long)f2bf(v.x)
                       | ((unsigned long long)f2bf(v.y) << 16)
                       | ((unsigned long long)f2bf(v.z) << 32)
                       | ((unsigned long long)f2bf(v.w) << 48);
  *(unsigned long long*)&out[i] = p;
}

__global__ void build_wcat(const float* __restrict__ wqkv, const float* __restrict__ wz,
                           const float* __restrict__ wb, const float* __restrict__ wa,
                           unsigned short* __restrict__ wcat) {
  long idx = (long)blockIdx.x * 256 + threadIdx.x;
  long e = idx * 4;
  long r = e >> 11;
  int cc = (int)(e & 2047);
  unsigned long long p = 0ULL;
  if (r < 12352) {
    const float* src;
    if (r < 8192)       src = wqkv + r * 2048;
    else if (r < 12288) src = wz + (r - 8192) * 2048;
    else if (r < 12320) src = wb + (r - 12288) * 2048;
    else                src = wa + (r - 12320) * 2048;
    float4 v = *(const float4*)&src[cc];
    p = (unsigned long long)f2bf(v.x)
      | ((unsigned long long)f2bf(v.y) << 16)
      | ((unsigned long long)f2bf(v.z) << 32)
      | ((unsigned long long)f2bf(v.w) << 48);
  }
  *(unsigned long long*)&wcat[e] = p;
}

// ---------------- GEMM: C[M,N] = A[M,K] * W[N,K]^T ----------------
template <bool BF16OUT>
__global__ __launch_bounds__(256) void gemm_bt(const unsigned short* __restrict__ A,
                                               const unsigned short* __restrict__ Bw,
                                               void* __restrict__ Cout,
                                               int N, int K) {
  __shared__ unsigned short lds[8192];
  const int tid = threadIdx.x;
  const int wid = tid >> 6;
  const int lane = tid & 63;
  const int m0 = blockIdx.y << 7;
  const int n0 = blockIdx.x << 7;
  const int wr = wid >> 1, wc = wid & 1;

  f32x4 acc[4][4] = {};

  const int srow = (wid << 4) + (lane >> 2);
  const int scol = (lane & 3) << 3;
  const unsigned short* gA0 = A + (long)(m0 + srow) * K + scol;
  const unsigned short* gA1 = A + (long)(m0 + 64 + srow) * K + scol;
  const unsigned short* gB0 = Bw + (long)(n0 + srow) * K + scol;
  const unsigned short* gB1 = Bw + (long)(n0 + 64 + srow) * K + scol;
  unsigned short* ldsA = &lds[wid << 9];
  unsigned short* ldsB = &lds[4096 + (wid << 9)];

  const int lrow = lane & 15;
  const int lk = (lane >> 4) << 3;

  for (int k0 = 0; k0 < K; k0 += 32) {
    __syncthreads();
    gload_lds16(gA0 + k0, ldsA);
    gload_lds16(gA1 + k0, ldsA + 2048);
    gload_lds16(gB0 + k0, ldsB);
    gload_lds16(gB1 + k0, ldsB + 2048);
    __syncthreads();
    short8 av[4], bv[4];
#pragma unroll
    for (int i = 0; i < 4; ++i) {
      av[i] = *(const short8*)&lds[((wr << 6) + (i << 4) + lrow) * 32 + lk];
      bv[i] = *(const short8*)&lds[4096 + ((wc << 6) + (i << 4) + lrow) * 32 + lk];
    }
#pragma unroll
    for (int i = 0; i < 4; ++i)
#pragma unroll
      for (int j = 0; j < 4; ++j)
        acc[i][j] = __builtin_amdgcn_mfma_f32_16x16x32_bf16(av[i], bv[j], acc[i][j], 0, 0, 0);
  }
  const int rbase = m0 + (wr << 6) + ((lane >> 4) << 2);
  const int cbase = n0 + (wc << 6) + (lane & 15);
#pragma unroll
  for (int i = 0; i < 4; ++i)
#pragma unroll
    for (int j = 0; j < 4; ++j)
#pragma unroll
      for (int r = 0; r < 4; ++r) {
        long idx = (long)(rbase + (i << 4) + r) * N + cbase + (j << 4);
        if (BF16OUT) ((unsigned short*)Cout)[idx] = f2bf(acc[i][j][r]);
        else         ((float*)Cout)[idx] = acc[i][j][r];
      }
}

// ---------------- depthwise causal conv1d + silu (8 channels/thread) ----------------
__global__ __launch_bounds__(256) void conv_silu(const unsigned short* __restrict__ C1,
                                                 const float* __restrict__ convw,
                                                 unsigned short* __restrict__ qb,
                                                 unsigned short* __restrict__ kb,
                                                 unsigned short* __restrict__ vb) {
  const int bid = blockIdx.x;             // 128 = cb(4) * tblk(16) * b(2)
  const int cb = bid & 3, tblk = (bid >> 2) & 15, b = bid >> 6;
  const int c0 = cb * 2048 + threadIdx.x * 8;
  float w0[8], w1[8], w2[8], w3[8];
#pragma unroll
  for (int j = 0; j < 8; ++j) {
    float4 wv = *(const float4*)&convw[(c0 + j) * 4];
    w0[j] = wv.x; w1[j] = wv.y; w2[j] = wv.z; w3[j] = wv.w;
  }
  const int t0 = tblk * 128;
  const long rowbase = ((long)b * TT) * N1PAD + c0;
  float x0[8], x1[8], x2[8];
#pragma unroll
  for (int j = 0; j < 8; ++j) { x0[j] = 0.f; x1[j] = 0.f; x2[j] = 0.f; }
  if (t0 >= 1) { ushort8 r = *(const ushort8*)&C1[rowbase + (long)(t0 - 1) * N1PAD];
#pragma unroll
    for (int j = 0; j < 8; ++j) x2[j] = bf2f(r[j]); }
  if (t0 >= 2) { ushort8 r = *(const ushort8*)&C1[rowbase + (long)(t0 - 2) * N1PAD];
#pragma unroll
    for (int j = 0; j < 8; ++j) x1[j] = bf2f(r[j]); }
  if (t0 >= 3) { ushort8 r = *(const ushort8*)&C1[rowbase + (long)(t0 - 3) * N1PAD];
#pragma unroll
    for (int j = 0; j < 8; ++j) x0[j] = bf2f(r[j]); }

  for (int t = t0; t < t0 + 128; ++t) {
    ushort8 rr = *(const ushort8*)&C1[rowbase + (long)t * N1PAD];
    ushort8 outp;
#pragma unroll
    for (int j = 0; j < 8; ++j) {
      float x3 = bf2f(rr[j]);
      float y = w0[j] * x0[j] + w1[j] * x1[j] + w2[j] * x2[j] + w3[j] * x3;
      y = y / (1.f + __expf(-y));
      outp[j] = f2bf(y);
      x0[j] = x1[j]; x1[j] = x2[j]; x2[j] = x3;
    }
    long m = (long)b * TT + t;
    if (cb == 0)      *(ushort8*)&qb[m * 2048 + threadIdx.x * 8] = outp;
    else if (cb == 1) *(ushort8*)&kb[m * 2048 + threadIdx.x * 8] = outp;
    else              *(ushort8*)&vb[m * 4096 + (cb - 2) * 2048 + threadIdx.x * 8] = outp;
  }
}

// ---------------- g (decay) and beta ----------------
__global__ void gbeta(const unsigned short* __restrict__ C1, const float* __restrict__ Alog,
                      const float* __restrict__ dtb, float* __restrict__ egb, float* __restrict__ betab) {
  int idx = blockIdx.x * 256 + threadIdx.x;   // < 131072
  int m = idx >> 5, h = idx & 31;
  float a = bf2f(C1[(long)m * N1PAD + 12320 + h]);
  float bl = bf2f(C1[(long)m * N1PAD + 12288 + h]);
  float xsp = a + dtb[h];
  float sp = (xsp > 20.f) ? xsp : log1pf(expf(xsp));
  egb[idx] = expf(-expf(Alog[h]) * sp);
  betab[idx] = 1.f / (1.f + expf(-bl));
}

// ---------------- l2 norm over DK=128 (one wave per head) ----------------
__global__ __launch_bounds__(256) void l2norm(unsigned short* __restrict__ buf, float scale) {
  int hid = blockIdx.x * 4 + (threadIdx.x >> 6);
  int lane = threadIdx.x & 63;
  long off = (long)hid * 128 + lane * 2;
  unsigned int u = *(unsigned int*)&buf[off];
  float a = bf2f((unsigned short)(u & 0xffff));
  float c = bf2f((unsigned short)(u >> 16));
  float ss = a * a + c * c;
#pragma unroll
  for (int mm = 1; mm < 64; mm <<= 1) ss += __shfl_xor(ss, mm);
  float sc = scale / fmaxf(sqrtf(ss), 1e-12f);
  unsigned int pk = (unsigned int)f2bf(a * sc) | ((unsigned int)f2bf(c * sc) << 16);
  *(unsigned int*)&buf[off] = pk;
}

// ---------------- gated delta rule scan ----------------
__global__ __launch_bounds__(256) void scan_kernel(const unsigned short* __restrict__ qb,
                                                   const unsigned short* __restrict__ kb,
                                                   const unsigned short* __restrict__ vb,
                                                   const float* __restrict__ egb,
                                                   const float* __restrict__ betab,
                                                   unsigned short* __restrict__ ob) {
  const int bi = blockIdx.x;   // 256 = vc(4) * h(32) * b(2)
  const int vc = bi & 3, h = (bi >> 2) & 31, b = bi >> 7;
  const int hk = h >> 1;
  const int tid = threadIdx.x;
  const int col = tid >> 3, ks = tid & 7;
  __shared__ float sb[2][292];
  float S[16];
#pragma unroll
  for (int i = 0; i < 16; ++i) S[i] = 0.f;

  const long kqoff = ((long)b * TT) * 2048 + hk * 128;
  const long voff  = ((long)b * TT) * 4096 + h * 128 + vc * 32;
  const long goff  = ((long)b * TT) * 32 + h;

  // stage step t into sb[bufi]: wave 0 only
#define STAGE(bufi, t)                                                              \
  do {                                                                              \
    if (tid < 16) {                                                                 \
      ushort8 r = *(const ushort8*)&kb[kqoff + (long)(t) * 2048 + tid * 8];         \
      _Pragma("unroll") for (int j = 0; j < 8; ++j) sb[bufi][tid * 8 + j] = bf2f(r[j]); \
    } else if (tid < 32) {                                                          \
      ushort8 r = *(const ushort8*)&qb[kqoff + (long)(t) * 2048 + (tid - 16) * 8];  \
      _Pragma("unroll") for (int j = 0; j < 8; ++j) sb[bufi][128 + (tid - 16) * 8 + j] = bf2f(r[j]); \
    } else if (tid < 36) {                                                          \
      ushort8 r = *(const ushort8*)&vb[voff + (long)(t) * 4096 + (tid - 32) * 8];   \
      _Pragma("unroll") for (int j = 0; j < 8; ++j) sb[bufi][256 + (tid - 32) * 8 + j] = bf2f(r[j]); \
    } else if (tid == 36) {                                                         \
      sb[bufi][288] = egb[goff + (long)(t) * 32];                                   \
      sb[bufi][289] = betab[goff + (long)(t) * 32];                                 \
    }                                                                               \
  } while (0)

  STAGE(0, 0);
  __syncthreads();

  int buf = 0;
  for (int t = 0; t < TT; ++t) {
    if (t + 1 < TT) STAGE(buf ^ 1, t + 1);
    float eg = sb[buf][288];
    float bt_ = sb[buf][289];
    float vv = sb[buf][256 + col];
    float kf[16], qf[16];
#pragma unroll
    for (int u = 0; u < 4; ++u) {
      float4 k4 = *(const float4*)&sb[buf][ks * 16 + u * 4];
      float4 q4 = *(const float4*)&sb[buf][128 + ks * 16 + u * 4];
      kf[u * 4 + 0] = k4.x; kf[u * 4 + 1] = k4.y; kf[u * 4 + 2] = k4.z; kf[u * 4 + 3] = k4.w;
      qf[u * 4 + 0] = q4.x; qf[u * 4 + 1] = q4.y; qf[u * 4 + 2] = q4.z; qf[u * 4 + 3] = q4.w;
    }
    float kv = 0.f;
#pragma unroll
    for (int i = 0; i < 16; ++i) { S[i] *= eg; kv += kf[i] * S[i]; }
    kv += __shfl_xor(kv, 1); kv += __shfl_xor(kv, 2); kv += __shfl_xor(kv, 4);
    float bv = bt_ * (vv - kv);
    float o = 0.f;
#pragma unroll
    for (int i = 0; i < 16; ++i) { S[i] += kf[i] * bv; o += qf[i] * S[i]; }
    o += __shfl_xor(o, 1); o += __shfl_xor(o, 2); o += __shfl_xor(o, 4);
    if (ks == 0) ob[((long)(b * TT + t) * 32 + h) * 128 + vc * 32 + col] = f2bf(o);
    __syncthreads();
    buf ^= 1;
  }
#undef STAGE
}

// ---------------- gated RMSNorm * silu(z) -> bf16 ----------------
__global__ __launch_bounds__(256) void norm_silu(const unsigned short* __restrict__ ob,
                                                 const unsigned short* __restrict__ C1,
                                                 const float* __restrict__ nw,
                                                 unsigned short* __restrict__ nrm) {
  int unit = blockIdx.x * 4 + (threadIdx.x >> 6);   // m*32+h
  int lane = threadIdx.x & 63;
  int m = unit >> 5, h = unit & 31;
  unsigned int uo = *(const unsigned int*)&ob[(long)unit * 128 + lane * 2];
  float o0 = bf2f((unsigned short)(uo & 0xffff));
  float o1 = bf2f((unsigned short)(uo >> 16));
  float ss = o0 * o0 + o1 * o1;
#pragma unroll
  for (int mm = 1; mm < 64; mm <<= 1) ss += __shfl_xor(ss, mm);
  float rs = rsqrtf(ss * (1.0f / 128.0f) + 1e-6f);
  unsigned int uz = *(const unsigned int*)&C1[(long)m * N1PAD + 8192 + h * 128 + lane * 2];
  float z0 = bf2f((unsigned short)(uz & 0xffff));
  float z1 = bf2f((unsigned short)(uz >> 16));
  float s0 = z0 / (1.f + expf(-z0));
  float s1 = z1 / (1.f + expf(-z1));
  float r0 = o0 * rs * nw[lane * 2] * s0;
  float r1 = o1 * rs * nw[lane * 2 + 1] * s1;
  unsigned int pk = (unsigned int)f2bf(r0) | ((unsigned int)f2bf(r1) << 16);
  *(unsigned int*)&nrm[(long)unit * 128 + lane * 2] = pk;
}

extern "C" void kernel_launch(void* const* d_in, const int* in_sizes, int n_in,
                              void* d_out, int out_size, void* d_ws, size_t ws_size,
                              hipStream_t stream) {
  const float* x    = (const float*)d_in[0];
  const float* Wqkv = (const float*)d_in[2];
  const float* Wz   = (const float*)d_in[3];
  const float* Wb   = (const float*)d_in[4];
  const float* Wa   = (const float*)d_in[5];
  const float* convw= (const float*)d_in[6];
  const float* dtb  = (const float*)d_in[7];
  const float* Alog = (const float*)d_in[8];
  const float* nw   = (const float*)d_in[9];
  const float* Wout = (const float*)d_in[10];
  float* out = (float*)d_out;

  char* ws = (char*)d_ws;
  // byte offsets (aliased regions; peak = ~194.5 MiB)
  const size_t OFF_C1    = 0;                    // bf16 [4096][12416]  = 101,711,872
  const size_t OFF_XB    = 101711872;            // bf16 [4096][2048]   = 16,777,216
  const size_t OFF_WCAT  = 118489088;            // bf16 [12416][2048]  = 50,855,936
  const size_t OFF_QB    = OFF_XB;               // bf16 [4096][2048]  (over xb, post-GEMM1)
  const size_t OFF_KB    = 118489088;            // bf16 [4096][2048]  (over wcat)
  const size_t OFF_VB    = 135266304;            // bf16 [4096][4096]  (over wcat)
  const size_t OFF_EG    = 169345024;            // f32  [4096][32]     = 524,288
  const size_t OFF_BE    = 169869312;            // f32  [4096][32]
  const size_t OFF_OB    = 170393600;            // bf16 [4096][32][128]= 33,554,432 (end 203,948,032)
  const size_t OFF_NRM   = OFF_QB;               // bf16 [4096][4096]  (over qb+kb, post-scan)
  const size_t OFF_WOUTB = OFF_VB;               // bf16 [2048][4096]  (over vb, post-scan)

  unsigned short* C1    = (unsigned short*)(ws + OFF_C1);
  unsigned short* xb    = (unsigned short*)(ws + OFF_XB);
  unsigned short* wcat  = (unsigned short*)(ws + OFF_WCAT);
  unsigned short* qb    = (unsigned short*)(ws + OFF_QB);
  unsigned short* kb    = (unsigned short*)(ws + OFF_KB);
  unsigned short* vb    = (unsigned short*)(ws + OFF_VB);
  float*          egb   = (float*)(ws + OFF_EG);
  float*          betab = (float*)(ws + OFF_BE);
  unsigned short* ob    = (unsigned short*)(ws + OFF_OB);
  unsigned short* nrm   = (unsigned short*)(ws + OFF_NRM);
  unsigned short* woutb = (unsigned short*)(ws + OFF_WOUTB);
  (void)ws_size; (void)in_sizes; (void)n_in; (void)out_size; (void)d_in;

  cvt_bf16<<<8192, 256, 0, stream>>>(x, xb);
  build_wcat<<<24832, 256, 0, stream>>>(Wqkv, Wz, Wb, Wa, wcat);
  gemm_bt<true><<<dim3(N1PAD / 128, M_ROWS / 128), 256, 0, stream>>>(xb, wcat, C1, N1PAD, 2048);
  conv_silu<<<128, 256, 0, stream>>>(C1, convw, qb, kb, vb);
  gbeta<<<512, 256, 0, stream>>>(C1, Alog, dtb, egb, betab);
  l2norm<<<16384, 256, 0, stream>>>(qb, 0.08838834764831845f);   // fold DK^-0.5 into q
  l2norm<<<16384, 256, 0, stream>>>(kb, 1.0f);
  scan_kernel<<<256, 256, 0, stream>>>(qb, kb, vb, egb, betab, ob);
  cvt_bf16<<<8192, 256, 0, stream>>>(Wout, woutb);
  norm_silu<<<32768, 256, 0, stream>>>(ob, C1, nw, nrm);
  gemm_bt<false><<<dim3(2048 / 128, M_ROWS / 128), 256, 0, stream>>>(nrm, woutb, out, 2048, 4096);
}

// Round 4
// 1488.284 us; speedup vs baseline: 2.4406x; 2.4406x over previous
//
#include <hip/hip_runtime.h>

// dims
#define BB 2
#define TT 2048
#define HID 2048
#define HK 16
#define HV 32
#define DK 128
#define DV 128
#define KW 4
#define KEY_DIM 2048
#define VAL_DIM 4096
#define CONV_DIM 8192
#define N1PAD 12416     // 12352 padded to 128
#define M_ROWS 4096     // B*T
#define CHUNK 32        // scan chunk (timesteps staged per barrier)

typedef __attribute__((ext_vector_type(8))) short short8;
typedef __attribute__((ext_vector_type(8))) unsigned short ushort8;
typedef __attribute__((ext_vector_type(4))) float f32x4;

__device__ __forceinline__ unsigned short f2bf(float f) {
  union { float f; unsigned int u; } v; v.f = f;
  unsigned int r = v.u + 0x7FFFu + ((v.u >> 16) & 1u);
  return (unsigned short)(r >> 16);
}
__device__ __forceinline__ float bf2f(unsigned short u) {
  union { unsigned int u; float f; } v; v.u = ((unsigned int)u) << 16; return v.f;
}
__device__ __forceinline__ float bitsf(unsigned int u) {
  union { unsigned int u; float f; } v; v.u = u; return v.f;
}

__device__ __forceinline__ void gload_lds16(const unsigned short* g, unsigned short* l) {
  __builtin_amdgcn_global_load_lds((const __attribute__((address_space(1))) unsigned int*)g,
                                   (__attribute__((address_space(3))) unsigned int*)l,
                                   16, 0, 0);
}
__device__ __forceinline__ void gload_lds4(const float* g, unsigned short* l) {
  __builtin_amdgcn_global_load_lds((const __attribute__((address_space(1))) unsigned int*)g,
                                   (__attribute__((address_space(3))) unsigned int*)l,
                                   4, 0, 0);
}

// ---------------- conversions ----------------
__global__ void cvt_bf16(const float* __restrict__ in, unsigned short* __restrict__ out) {
  long i = ((long)blockIdx.x * 256 + threadIdx.x) * 4;
  float4 v = *(const float4*)&in[i];
  unsigned long long p = (unsigned long long)f2bf(v.x)
                       | ((unsigned long long)f2bf(v.y) << 16)
                       | ((unsigned long long)f2bf(v.z) << 32)
                       | ((unsigned long long)f2bf(v.w) << 48);
  *(unsigned long long*)&out[i] = p;
}

__global__ void build_wcat(const float* __restrict__ wqkv, const float* __restrict__ wz,
                           const float* __restrict__ wb, const float* __restrict__ wa,
                           unsigned short* __restrict__ wcat) {
  long idx = (long)blockIdx.x * 256 + threadIdx.x;
  long e = idx * 4;
  long r = e >> 11;
  int cc = (int)(e & 2047);
  unsigned long long p = 0ULL;
  if (r < 12352) {
    const float* src;
    if (r < 8192)       src = wqkv + r * 2048;
    else if (r < 12288) src = wz + (r - 8192) * 2048;
    else if (r < 12320) src = wb + (r - 12288) * 2048;
    else                src = wa + (r - 12320) * 2048;
    float4 v = *(const float4*)&src[cc];
    p = (unsigned long long)f2bf(v.x)
      | ((unsigned long long)f2bf(v.y) << 16)
      | ((unsigned long long)f2bf(v.z) << 32)
      | ((unsigned long long)f2bf(v.w) << 48);
  }
  *(unsigned long long*)&wcat[e] = p;
}

// ---------------- GEMM: C[M,N] = A[M,K] * W[N,K]^T ----------------
template <bool BF16OUT>
__global__ __launch_bounds__(256) void gemm_bt(const unsigned short* __restrict__ A,
                                               const unsigned short* __restrict__ Bw,
                                               void* __restrict__ Cout,
                                               int N, int K) {
  __shared__ unsigned short lds[8192];
  const int tid = threadIdx.x;
  const int wid = tid >> 6;
  const int lane = tid & 63;
  const int m0 = blockIdx.y << 7;
  const int n0 = blockIdx.x << 7;
  const int wr = wid >> 1, wc = wid & 1;

  f32x4 acc[4][4] = {};

  const int srow = (wid << 4) + (lane >> 2);
  const int scol = (lane & 3) << 3;
  const unsigned short* gA0 = A + (long)(m0 + srow) * K + scol;
  const unsigned short* gA1 = A + (long)(m0 + 64 + srow) * K + scol;
  const unsigned short* gB0 = Bw + (long)(n0 + srow) * K + scol;
  const unsigned short* gB1 = Bw + (long)(n0 + 64 + srow) * K + scol;
  unsigned short* ldsA = &lds[wid << 9];
  unsigned short* ldsB = &lds[4096 + (wid << 9)];

  const int lrow = lane & 15;
  const int lk = (lane >> 4) << 3;

  for (int k0 = 0; k0 < K; k0 += 32) {
    __syncthreads();
    gload_lds16(gA0 + k0, ldsA);
    gload_lds16(gA1 + k0, ldsA + 2048);
    gload_lds16(gB0 + k0, ldsB);
    gload_lds16(gB1 + k0, ldsB + 2048);
    __syncthreads();
    short8 av[4], bv[4];
#pragma unroll
    for (int i = 0; i < 4; ++i) {
      av[i] = *(const short8*)&lds[((wr << 6) + (i << 4) + lrow) * 32 + lk];
      bv[i] = *(const short8*)&lds[4096 + ((wc << 6) + (i << 4) + lrow) * 32 + lk];
    }
#pragma unroll
    for (int i = 0; i < 4; ++i)
#pragma unroll
      for (int j = 0; j < 4; ++j)
        acc[i][j] = __builtin_amdgcn_mfma_f32_16x16x32_bf16(av[i], bv[j], acc[i][j], 0, 0, 0);
  }
  const int rbase = m0 + (wr << 6) + ((lane >> 4) << 2);
  const int cbase = n0 + (wc << 6) + (lane & 15);
#pragma unroll
  for (int i = 0; i < 4; ++i)
#pragma unroll
    for (int j = 0; j < 4; ++j)
#pragma unroll
      for (int r = 0; r < 4; ++r) {
        long idx = (long)(rbase + (i << 4) + r) * N + cbase + (j << 4);
        if (BF16OUT) ((unsigned short*)Cout)[idx] = f2bf(acc[i][j][r]);
        else         ((float*)Cout)[idx] = acc[i][j][r];
      }
}

// ---------------- depthwise causal conv1d + silu (8 channels/thread) ----------------
__global__ __launch_bounds__(256) void conv_silu(const unsigned short* __restrict__ C1,
                                                 const float* __restrict__ convw,
                                                 unsigned short* __restrict__ qb,
                                                 unsigned short* __restrict__ kb,
                                                 unsigned short* __restrict__ vb) {
  const int bid = blockIdx.x;             // 512 = cb(4) * tblk(64) * b(2)
  const int cb = bid & 3, tblk = (bid >> 2) & 63, b = bid >> 8;
  const int c0 = cb * 2048 + threadIdx.x * 8;
  float w0[8], w1[8], w2[8], w3[8];
#pragma unroll
  for (int j = 0; j < 8; ++j) {
    float4 wv = *(const float4*)&convw[(c0 + j) * 4];
    w0[j] = wv.x; w1[j] = wv.y; w2[j] = wv.z; w3[j] = wv.w;
  }
  const int t0 = tblk * 32;
  const long rowbase = ((long)b * TT) * N1PAD + c0;
  float x0[8], x1[8], x2[8];
#pragma unroll
  for (int j = 0; j < 8; ++j) { x0[j] = 0.f; x1[j] = 0.f; x2[j] = 0.f; }
  if (t0 >= 1) { ushort8 r = *(const ushort8*)&C1[rowbase + (long)(t0 - 1) * N1PAD];
#pragma unroll
    for (int j = 0; j < 8; ++j) x2[j] = bf2f(r[j]); }
  if (t0 >= 2) { ushort8 r = *(const ushort8*)&C1[rowbase + (long)(t0 - 2) * N1PAD];
#pragma unroll
    for (int j = 0; j < 8; ++j) x1[j] = bf2f(r[j]); }
  if (t0 >= 3) { ushort8 r = *(const ushort8*)&C1[rowbase + (long)(t0 - 3) * N1PAD];
#pragma unroll
    for (int j = 0; j < 8; ++j) x0[j] = bf2f(r[j]); }

  for (int t = t0; t < t0 + 32; ++t) {
    ushort8 rr = *(const ushort8*)&C1[rowbase + (long)t * N1PAD];
    ushort8 outp;
#pragma unroll
    for (int j = 0; j < 8; ++j) {
      float x3 = bf2f(rr[j]);
      float y = w0[j] * x0[j] + w1[j] * x1[j] + w2[j] * x2[j] + w3[j] * x3;
      y = y / (1.f + __expf(-y));
      outp[j] = f2bf(y);
      x0[j] = x1[j]; x1[j] = x2[j]; x2[j] = x3;
    }
    long m = (long)b * TT + t;
    if (cb == 0)      *(ushort8*)&qb[m * 2048 + threadIdx.x * 8] = outp;
    else if (cb == 1) *(ushort8*)&kb[m * 2048 + threadIdx.x * 8] = outp;
    else              *(ushort8*)&vb[m * 4096 + (cb - 2) * 2048 + threadIdx.x * 8] = outp;
  }
}

// ---------------- g (decay) and beta ----------------
__global__ void gbeta(const unsigned short* __restrict__ C1, const float* __restrict__ Alog,
                      const float* __restrict__ dtb, float* __restrict__ egb, float* __restrict__ betab) {
  int idx = blockIdx.x * 256 + threadIdx.x;   // < 131072
  int m = idx >> 5, h = idx & 31;
  float a = bf2f(C1[(long)m * N1PAD + 12320 + h]);
  float bl = bf2f(C1[(long)m * N1PAD + 12288 + h]);
  float xsp = a + dtb[h];
  float sp = (xsp > 20.f) ? xsp : log1pf(expf(xsp));
  egb[idx] = expf(-expf(Alog[h]) * sp);
  betab[idx] = 1.f / (1.f + expf(-bl));
}

// ---------------- l2 norm over DK=128 (one wave per head) ----------------
__global__ __launch_bounds__(256) void l2norm(unsigned short* __restrict__ buf, float scale) {
  int hid = blockIdx.x * 4 + (threadIdx.x >> 6);
  int lane = threadIdx.x & 63;
  long off = (long)hid * 128 + lane * 2;
  unsigned int u = *(unsigned int*)&buf[off];
  float a = bf2f((unsigned short)(u & 0xffff));
  float c = bf2f((unsigned short)(u >> 16));
  float ss = a * a + c * c;
#pragma unroll
  for (int mm = 1; mm < 64; mm <<= 1) ss += __shfl_xor(ss, mm);
  float sc = scale / fmaxf(sqrtf(ss), 1e-12f);
  unsigned int pk = (unsigned int)f2bf(a * sc) | ((unsigned int)f2bf(c * sc) << 16);
  *(unsigned int*)&buf[off] = pk;
}

// ---------------- gated delta rule scan (chunked staging, register inner loop) ----------------
// LDS buffer layout (ushort units), per buffer (9344 ush = 18688 B):
//   k  [CHUNK][128] @ 0        (8192 B = 2 rounds x 4 waves x 1024 B)
//   q  [CHUNK][128] @ 4096
//   v  [CHUNK][32]  @ 8192     (2048 B = waves 0,1 x 1024 B)
//   g,b f32 [32+32] @ 9216     (wave 2, 4 B/lane)
__global__ __launch_bounds__(256) void scan_kernel(const unsigned short* __restrict__ qb,
                                                   const unsigned short* __restrict__ kb,
                                                   const unsigned short* __restrict__ vb,
                                                   const float* __restrict__ egb,
                                                   const float* __restrict__ betab,
                                                   unsigned short* __restrict__ ob) {
  const int bi = blockIdx.x;   // 256 = vc(4) * h(32) * b(2)
  const int vc = bi & 3, h = (bi >> 2) & 31, b = bi >> 7;
  const int hk = h >> 1;
  const int tid = threadIdx.x;
  const int wid = tid >> 6, lane = tid & 63;
  const int col = tid >> 3, ks = tid & 7;

  __shared__ unsigned short sl[2][9344];

  float S[16];
#pragma unroll
  for (int i = 0; i < 16; ++i) S[i] = 0.f;

  const long kqoff = ((long)b * TT) * 2048 + hk * 128;
  const long voff  = ((long)b * TT) * 4096 + h * 128 + vc * 32;
  const long goff  = ((long)b * TT) * 32 + h;

  // stage chunk starting at t0 into buffer bf (async global->LDS).
  // global_load_lds writes lane l's payload at lds_base + l*size (linear),
  // so the per-lane GLOBAL address must follow the same linear order.
  auto stage = [&](int bf, int t0) {
    unsigned short* base = sl[bf];
#pragma unroll
    for (int r = 0; r < 2; ++r) {
      int i = r * 256 + tid;                 // dest byte = i*16 within region
      int step = i >> 4, frag = i & 15;
      gload_lds16(kb + kqoff + (long)(t0 + step) * 2048 + frag * 8,
                  base + (r * 4 + wid) * 512);
      gload_lds16(qb + kqoff + (long)(t0 + step) * 2048 + frag * 8,
                  base + 4096 + (r * 4 + wid) * 512);
    }
    if (wid < 2) {
      // v: 2048 B region, waves 0+1; dest byte = (wid*64+lane)*16
      int step = wid * 16 + (lane >> 2), frag = lane & 3;
      gload_lds16(vb + voff + (long)(t0 + step) * 4096 + frag * 8,
                  base + 8192 + wid * 512);
    } else if (wid == 2) {
      // g,b: 256 B region; dest byte = lane*4
      const float* gp = (lane < 32) ? (egb + goff + (long)(t0 + lane) * 32)
                                    : (betab + goff + (long)(t0 + lane - 32) * 32);
      gload_lds4(gp, base + 9216);
    }
  };

  stage(0, 0);
  __syncthreads();

  const int kqo = ks * 16;        // ushort offset of this thread's fragment within a row
  int bf = 0;
  for (int c = 0; c < TT / CHUNK; ++c) {
    if (c + 1 < TT / CHUNK) stage(bf ^ 1, (c + 1) * CHUNK);
    const unsigned short* base = sl[bf];
    const float* gf = (const float*)(base + 9216);
    long obase = ((long)(b * TT + c * CHUNK) * 32 + h) * 128 + vc * 32 + col;
#pragma unroll 4
    for (int s = 0; s < CHUNK; ++s) {
      const unsigned short* kp = base + s * 128 + kqo;
      const unsigned short* qp = base + 4096 + s * 128 + kqo;
      uint4 ka = *(const uint4*)kp;
      uint4 kc = *(const uint4*)(kp + 8);
      uint4 qa = *(const uint4*)qp;
      uint4 qc = *(const uint4*)(qp + 8);
      float eg = gf[s];
      float bt = gf[32 + s];
      float vv = bf2f(base[8192 + s * 32 + col]);
      float kf[16], qf[16];
#define UNP(u4, f, o)                                                   \
      f[o+0]=bitsf((u4).x<<16); f[o+1]=bitsf((u4).x&0xffff0000u);       \
      f[o+2]=bitsf((u4).y<<16); f[o+3]=bitsf((u4).y&0xffff0000u);       \
      f[o+4]=bitsf((u4).z<<16); f[o+5]=bitsf((u4).z&0xffff0000u);       \
      f[o+6]=bitsf((u4).w<<16); f[o+7]=bitsf((u4).w&0xffff0000u);
      UNP(ka, kf, 0) UNP(kc, kf, 8) UNP(qa, qf, 0) UNP(qc, qf, 8)
#undef UNP
      // decay
#pragma unroll
      for (int i = 0; i < 16; ++i) S[i] *= eg;
      // kv = dot(k, S) over 128 (16 local + 8-lane reduce), 4-way split chains
      float kv0 = kf[0] * S[0], kv1 = kf[1] * S[1], kv2 = kf[2] * S[2], kv3 = kf[3] * S[3];
#pragma unroll
      for (int i = 4; i < 16; i += 4) {
        kv0 = fmaf(kf[i + 0], S[i + 0], kv0);
        kv1 = fmaf(kf[i + 1], S[i + 1], kv1);
        kv2 = fmaf(kf[i + 2], S[i + 2], kv2);
        kv3 = fmaf(kf[i + 3], S[i + 3], kv3);
      }
      float kv = (kv0 + kv1) + (kv2 + kv3);
      kv += __shfl_xor(kv, 1); kv += __shfl_xor(kv, 2); kv += __shfl_xor(kv, 4);
      float bv = bt * (vv - kv);
      // S += k * bv;  o = dot(q, S)
      float o0, o1, o2, o3;
      S[0] = fmaf(kf[0], bv, S[0]); o0 = qf[0] * S[0];
      S[1] = fmaf(kf[1], bv, S[1]); o1 = qf[1] * S[1];
      S[2] = fmaf(kf[2], bv, S[2]); o2 = qf[2] * S[2];
      S[3] = fmaf(kf[3], bv, S[3]); o3 = qf[3] * S[3];
#pragma unroll
      for (int i = 4; i < 16; i += 4) {
        S[i + 0] = fmaf(kf[i + 0], bv, S[i + 0]); o0 = fmaf(qf[i + 0], S[i + 0], o0);
        S[i + 1] = fmaf(kf[i + 1], bv, S[i + 1]); o1 = fmaf(qf[i + 1], S[i + 1], o1);
        S[i + 2] = fmaf(kf[i + 2], bv, S[i + 2]); o2 = fmaf(qf[i + 2], S[i + 2], o2);
        S[i + 3] = fmaf(kf[i + 3], bv, S[i + 3]); o3 = fmaf(qf[i + 3], S[i + 3], o3);
      }
      float o = (o0 + o1) + (o2 + o3);
      o += __shfl_xor(o, 1); o += __shfl_xor(o, 2); o += __shfl_xor(o, 4);
      if (ks == 0) ob[obase + (long)s * 4096] = f2bf(o);
    }
    __syncthreads();
    bf ^= 1;
  }
}

// ---------------- gated RMSNorm * silu(z) -> bf16 ----------------
__global__ __launch_bounds__(256) void norm_silu(const unsigned short* __restrict__ ob,
                                                 const unsigned short* __restrict__ C1,
                                                 const float* __restrict__ nw,
                                                 unsigned short* __restrict__ nrm) {
  int unit = blockIdx.x * 4 + (threadIdx.x >> 6);   // m*32+h
  int lane = threadIdx.x & 63;
  int m = unit >> 5, h = unit & 31;
  unsigned int uo = *(const unsigned int*)&ob[(long)unit * 128 + lane * 2];
  float o0 = bf2f((unsigned short)(uo & 0xffff));
  float o1 = bf2f((unsigned short)(uo >> 16));
  float ss = o0 * o0 + o1 * o1;
#pragma unroll
  for (int mm = 1; mm < 64; mm <<= 1) ss += __shfl_xor(ss, mm);
  float rs = rsqrtf(ss * (1.0f / 128.0f) + 1e-6f);
  unsigned int uz = *(const unsigned int*)&C1[(long)m * N1PAD + 8192 + h * 128 + lane * 2];
  float z0 = bf2f((unsigned short)(uz & 0xffff));
  float z1 = bf2f((unsigned short)(uz >> 16));
  float s0 = z0 / (1.f + expf(-z0));
  float s1 = z1 / (1.f + expf(-z1));
  float r0 = o0 * rs * nw[lane * 2] * s0;
  float r1 = o1 * rs * nw[lane * 2 + 1] * s1;
  unsigned int pk = (unsigned int)f2bf(r0) | ((unsigned int)f2bf(r1) << 16);
  *(unsigned int*)&nrm[(long)unit * 128 + lane * 2] = pk;
}

extern "C" void kernel_launch(void* const* d_in, const int* in_sizes, int n_in,
                              void* d_out, int out_size, void* d_ws, size_t ws_size,
                              hipStream_t stream) {
  const float* x    = (const float*)d_in[0];
  const float* Wqkv = (const float*)d_in[2];
  const float* Wz   = (const float*)d_in[3];
  const float* Wb   = (const float*)d_in[4];
  const float* Wa   = (const float*)d_in[5];
  const float* convw= (const float*)d_in[6];
  const float* dtb  = (const float*)d_in[7];
  const float* Alog = (const float*)d_in[8];
  const float* nw   = (const float*)d_in[9];
  const float* Wout = (const float*)d_in[10];
  float* out = (float*)d_out;

  char* ws = (char*)d_ws;
  const size_t OFF_C1    = 0;                    // bf16 [4096][12416]
  const size_t OFF_XB    = 101711872;            // bf16 [4096][2048]
  const size_t OFF_WCAT  = 118489088;            // bf16 [12416][2048]
  const size_t OFF_QB    = OFF_XB;               // over xb (post-GEMM1)
  const size_t OFF_KB    = 118489088;            // over wcat
  const size_t OFF_VB    = 135266304;            // over wcat
  const size_t OFF_EG    = 169345024;            // f32  [4096][32]
  const size_t OFF_BE    = 169869312;
  const size_t OFF_OB    = 170393600;            // bf16 [4096][32][128]
  const size_t OFF_NRM   = OFF_QB;               // over qb+kb (post-scan)
  const size_t OFF_WOUTB = OFF_VB;               // over vb (post-scan)

  unsigned short* C1    = (unsigned short*)(ws + OFF_C1);
  unsigned short* xb    = (unsigned short*)(ws + OFF_XB);
  unsigned short* wcat  = (unsigned short*)(ws + OFF_WCAT);
  unsigned short* qb    = (unsigned short*)(ws + OFF_QB);
  unsigned short* kb    = (unsigned short*)(ws + OFF_KB);
  unsigned short* vb    = (unsigned short*)(ws + OFF_VB);
  float*          egb   = (float*)(ws + OFF_EG);
  float*          betab = (float*)(ws + OFF_BE);
  unsigned short* ob    = (unsigned short*)(ws + OFF_OB);
  unsigned short* nrm   = (unsigned short*)(ws + OFF_NRM);
  unsigned short* woutb = (unsigned short*)(ws + OFF_WOUTB);
  (void)ws_size; (void)in_sizes; (void)n_in; (void)out_size;

  cvt_bf16<<<8192, 256, 0, stream>>>(x, xb);
  build_wcat<<<24832, 256, 0, stream>>>(Wqkv, Wz, Wb, Wa, wcat);
  gemm_bt<true><<<dim3(N1PAD / 128, M_ROWS / 128), 256, 0, stream>>>(xb, wcat, C1, N1PAD, 2048);
  conv_silu<<<512, 256, 0, stream>>>(C1, convw, qb, kb, vb);
  gbeta<<<512, 256, 0, stream>>>(C1, Alog, dtb, egb, betab);
  l2norm<<<16384, 256, 0, stream>>>(qb, 0.08838834764831845f);   // fold DK^-0.5 into q
  l2norm<<<16384, 256, 0, stream>>>(kb, 1.0f);
  scan_kernel<<<256, 256, 0, stream>>>(qb, kb, vb, egb, betab, ob);
  cvt_bf16<<<8192, 256, 0, stream>>>(Wout, woutb);
  norm_silu<<<32768, 256, 0, stream>>>(ob, C1, nw, nrm);
  gemm_bt<false><<<dim3(2048 / 128, M_ROWS / 128), 256, 0, stream>>>(nrm, woutb, out, 2048, 4096);
}